// Round 3
// baseline (1273.581 us; speedup 1.0000x reference)
//
#include <hip/hip_runtime.h>

// ---------------------------------------------------------------------------
// ROUND 2 — all-fp32 diagnostic build (no f16, no MFMA).
// Purpose: discriminate "structural bug in skeleton" vs "f16/MFMA subsystem".
// Algorithm restructured via linearity of layer-1:
//   x1 = relu( sum_l g[l]*(PQ[l,i,:] + PK[l,j,:]) + b1 )
// where PQ[l,b,i,n] = Q_all[l,b,i,:].W1[:256,n], PK[l,b,j,n] = K_all.W1[256:,n]
// Kernels:
//   k_proj_f32 : Q_all/K_all = hs @ W + bias (28 GEMMs of 300x256x256, fp32)
//   k_gqk      : gq/gk wave-reduce dots
//   k_pq_f32   : PQ/PK = Q_all/K_all @ W1-half (28 GEMMs, fp32)
//   k_fused_f32: gates -> x1 (14 FMA/elem) -> relu -> layer2 (64x256x256
//                reg-tiled fp32) -> relu -> layer3 dot -> store 6 copies
// ---------------------------------------------------------------------------

// ---------------- k_proj_f32 ----------------------------------------------
// grid 280 = 28 sub-gemms x 10 row-tiles of 32.  block 256.
__global__ __launch_bounds__(256) void k_proj_f32(
    const float* __restrict__ hs,
    const float* __restrict__ Wq, const float* __restrict__ bq,
    const float* __restrict__ Wk, const float* __restrict__ bk,
    const float* __restrict__ Wsub, const float* __restrict__ bsub,
    const float* __restrict__ Wobj, const float* __restrict__ bobj,
    float* __restrict__ QA, float* __restrict__ KA)
{
    __shared__ float hsT[256][34];   // [d][r], pad->2-way banks
    int bid = blockIdx.x;
    int s = bid / 10, rt = bid - s * 10;
    int m0 = rt * 32;
    int qk = s & 1, rr = s >> 1;
    int l = rr % 7, b = rr / 7;
    int hs_l = (l < 6) ? l : 5;
    const float* src = hs + (hs_l * 2 + b) * 76800;
    const float* W; const float* bias;
    if (l < 6) { W = (qk ? Wk : Wq) + l * 65536; bias = (qk ? bk : bq) + l * 256; }
    else       { W = qk ? Wobj : Wsub; bias = qk ? bobj : bsub; }
    float* dst = (qk ? KA : QA) + (l * 2 + b) * 76800;

    int t = threadIdx.x;
    #pragma unroll 4
    for (int r = 0; r < 32; ++r) {
        int m = m0 + r; if (m > 299) m = 299;     // clamp; stores masked
        hsT[t][r] = src[m * 256 + t];             // coalesced over t=d
    }
    __syncthreads();

    int lane = t & 63, q = t >> 6;
    int ri = lane >> 2, ci = lane & 3;            // rows 2ri..+1, cols c0..+15
    int c0 = q * 64 + ci * 16;
    float acc[2][16] = {};
    for (int d = 0; d < 256; ++d) {
        float a0 = hsT[d][2 * ri + 0];
        float a1 = hsT[d][2 * ri + 1];
        const float* wp = W + d * 256 + c0;
        float4 w0 = *(const float4*)(wp + 0);
        float4 w1 = *(const float4*)(wp + 4);
        float4 w2 = *(const float4*)(wp + 8);
        float4 w3 = *(const float4*)(wp + 12);
        float wv[16] = {w0.x, w0.y, w0.z, w0.w, w1.x, w1.y, w1.z, w1.w,
                        w2.x, w2.y, w2.z, w2.w, w3.x, w3.y, w3.z, w3.w};
        #pragma unroll
        for (int cc = 0; cc < 16; ++cc) {
            acc[0][cc] += a0 * wv[cc];
            acc[1][cc] += a1 * wv[cc];
        }
    }
    #pragma unroll
    for (int r2 = 0; r2 < 2; ++r2) {
        int m = m0 + 2 * ri + r2;
        if (m < 300) {
            #pragma unroll
            for (int cc = 0; cc < 16; ++cc)
                dst[m * 256 + c0 + cc] = acc[r2][cc] + bias[c0 + cc];
        }
    }
}

// ---------------- k_gqk ---------------------------------------------------
// grid 2100 x 256 : 8400 wave-rows.  g_ws[qk][l][b][q] = row . (wa|wb)
__global__ __launch_bounds__(256) void k_gqk(
    const float* __restrict__ QA, const float* __restrict__ KA,
    const float* __restrict__ Wg, float* __restrict__ g_ws)
{
    int gid = blockIdx.x * 4 + (threadIdx.x >> 6);
    int lane = threadIdx.x & 63;
    int qk = gid / 4200, rid = gid - qk * 4200;
    const float* row = (qk ? KA : QA) + rid * 256 + lane * 4;
    const float* w = Wg + qk * 256 + lane * 4;
    float4 a = *(const float4*)row;
    float4 wv = *(const float4*)w;
    float sum = a.x * wv.x + a.y * wv.y + a.z * wv.z + a.w * wv.w;
    #pragma unroll
    for (int off = 1; off < 64; off <<= 1) sum += __shfl_xor(sum, off);
    if (lane == 0) g_ws[gid] = sum;
}

// ---------------- k_pq_f32 ------------------------------------------------
// grid 280: PQ/PK[qk][l][b][row][n] = (QA|KA)row . W1[qk*256 + d][n]
__global__ __launch_bounds__(256) void k_pq_f32(
    const float* __restrict__ QA, const float* __restrict__ KA,
    const float* __restrict__ W1, float* __restrict__ Pws)
{
    __shared__ float xT[256][34];
    int bid = blockIdx.x;
    int s = bid / 10, rt = bid - s * 10;
    int m0 = rt * 32;
    int qk = s & 1, rr = s >> 1;
    int l = rr % 7, b = rr / 7;
    const float* src = (qk ? KA : QA) + (l * 2 + b) * 76800;
    const float* W = W1 + qk * 65536;             // rows 0..255 / 256..511
    float* dst = Pws + (qk * 4200 + (l * 2 + b) * 300) * 256;

    int t = threadIdx.x;
    #pragma unroll 4
    for (int r = 0; r < 32; ++r) {
        int m = m0 + r; if (m > 299) m = 299;
        xT[t][r] = src[m * 256 + t];
    }
    __syncthreads();

    int lane = t & 63, q = t >> 6;
    int ri = lane >> 2, ci = lane & 3;
    int c0 = q * 64 + ci * 16;
    float acc[2][16] = {};
    for (int d = 0; d < 256; ++d) {
        float a0 = xT[d][2 * ri + 0];
        float a1 = xT[d][2 * ri + 1];
        const float* wp = W + d * 256 + c0;
        float4 w0 = *(const float4*)(wp + 0);
        float4 w1 = *(const float4*)(wp + 4);
        float4 w2 = *(const float4*)(wp + 8);
        float4 w3 = *(const float4*)(wp + 12);
        float wv[16] = {w0.x, w0.y, w0.z, w0.w, w1.x, w1.y, w1.z, w1.w,
                        w2.x, w2.y, w2.z, w2.w, w3.x, w3.y, w3.z, w3.w};
        #pragma unroll
        for (int cc = 0; cc < 16; ++cc) {
            acc[0][cc] += a0 * wv[cc];
            acc[1][cc] += a1 * wv[cc];
        }
    }
    #pragma unroll
    for (int r2 = 0; r2 < 2; ++r2) {
        int m = m0 + 2 * ri + r2;
        if (m < 300) {
            #pragma unroll
            for (int cc = 0; cc < 16; ++cc)
                dst[m * 256 + c0 + cc] = acc[r2][cc];   // no bias here
        }
    }
}

// ---------------- k_fused_f32 ---------------------------------------------
// grid 2*38*38 = 2888, block 256.  LDS ~143 KB -> 1 block/CU.
__global__ __launch_bounds__(256) void k_fused_f32(
    const float* __restrict__ Pws, const float* __restrict__ g_ws,
    const float* __restrict__ b1, const float* __restrict__ W2,
    const float* __restrict__ b2, const float* __restrict__ W3,
    const float* __restrict__ b3, const float* __restrict__ bg,
    float* __restrict__ out)
{
    __shared__ float gate[7][64];
    __shared__ float PQs[4][8][256];
    __shared__ float PKs[4][8][256];
    __shared__ float X1T[256][73];     // [d][r], pad 73 -> conflict-free
    __shared__ float red[4][64];

    int t = threadIdx.x;
    int bid = blockIdx.x;
    int b = bid / 1444, rem = bid - b * 1444;
    int it = rem / 38, jt = rem - it * 38;
    int i0 = it * 8, j0 = jt * 8;

    // ---- gates: gate[l][r], r = (i_off<<3)|j_off ----
    float bg0 = bg[0];
    for (int task = t; task < 448; task += 256) {
        int l = task >> 6, row = task & 63;
        int i = i0 + (row >> 3); if (i > 299) i = 299;
        int j = j0 + (row & 7);  if (j > 299) j = 299;
        float z = g_ws[l * 600 + b * 300 + i] + g_ws[4200 + l * 600 + b * 300 + j] + bg0;
        gate[l][row] = 1.0f / (1.0f + expf(-z));
    }
    __syncthreads();

    // ---- x1 build in 2 chunks of l (stage PQ/PK slices, accumulate) ----
    for (int ch = 0; ch < 2; ++ch) {
        int l0 = ch ? 4 : 0;
        int cnt = ch ? 3 : 4;
        for (int idx = t; idx < cnt * 2048; idx += 256) {
            int lc = idx >> 11;
            int io = (idx >> 8) & 7;
            int n = idx & 255;
            int l = l0 + lc;
            int i = i0 + io; if (i > 299) i = 299;
            int j = j0 + io; if (j > 299) j = 299;
            PQs[lc][io][n] = Pws[((l * 2 + b) * 300 + i) * 256 + n];
            PKs[lc][io][n] = Pws[1075200 + ((l * 2 + b) * 300 + j) * 256 + n];
        }
        __syncthreads();
        int n = t;
        #pragma unroll 1
        for (int r = 0; r < 64; ++r) {
            float v = 0.f;
            for (int lc = 0; lc < cnt; ++lc) {
                float g = gate[l0 + lc][r];
                v += g * (PQs[lc][r >> 3][n] + PKs[lc][r & 7][n]);
            }
            if (ch == 0) X1T[n][r] = v;
            else         X1T[n][r] += v;
        }
        __syncthreads();   // before re-staging / before layer2
    }

    // ---- relu(x1 + b1), in place (thread owns X1T row n) ----
    {
        int n = t;
        float bb = b1[n];
        #pragma unroll 1
        for (int r = 0; r < 64; ++r) {
            float v = X1T[n][r] + bb;
            X1T[n][r] = v > 0.f ? v : 0.f;
        }
    }
    __syncthreads();

    // ---- layer 2 (64x256 @ 256x256, reg-tiled 4x16) + layer 3 fused ----
    int lane = t & 63, q = t >> 6;
    int ri = lane >> 2, ci = lane & 3;    // rows 4ri..+3, cols c0..+15
    int c0 = q * 64 + ci * 16;
    float acc[4][16] = {};
    for (int d = 0; d < 256; ++d) {
        float a0 = X1T[d][4 * ri + 0];
        float a1 = X1T[d][4 * ri + 1];
        float a2 = X1T[d][4 * ri + 2];
        float a3 = X1T[d][4 * ri + 3];
        const float* wp = W2 + d * 256 + c0;
        float4 w0 = *(const float4*)(wp + 0);
        float4 w1 = *(const float4*)(wp + 4);
        float4 w2 = *(const float4*)(wp + 8);
        float4 w3 = *(const float4*)(wp + 12);
        float wv[16] = {w0.x, w0.y, w0.z, w0.w, w1.x, w1.y, w1.z, w1.w,
                        w2.x, w2.y, w2.z, w2.w, w3.x, w3.y, w3.z, w3.w};
        #pragma unroll
        for (int cc = 0; cc < 16; ++cc) {
            acc[0][cc] += a0 * wv[cc];
            acc[1][cc] += a1 * wv[cc];
            acc[2][cc] += a2 * wv[cc];
            acc[3][cc] += a3 * wv[cc];
        }
    }
    // layer 3 partials: relu(acc + b2) . W3 over this thread's 16 cols
    float p[4];
    #pragma unroll
    for (int r2 = 0; r2 < 4; ++r2) {
        float sum = 0.f;
        #pragma unroll
        for (int cc = 0; cc < 16; ++cc) {
            float v = acc[r2][cc] + b2[c0 + cc];
            v = v > 0.f ? v : 0.f;
            sum += v * W3[c0 + cc];
        }
        p[r2] = sum;
    }
    #pragma unroll
    for (int r2 = 0; r2 < 4; ++r2) {
        p[r2] += __shfl_xor(p[r2], 1);   // sum over ci
        p[r2] += __shfl_xor(p[r2], 2);
    }
    if (ci == 0) {
        #pragma unroll
        for (int r2 = 0; r2 < 4; ++r2)
            red[q][4 * ri + r2] = p[r2];
    }
    __syncthreads();
    if (t < 64) {
        int r = t;
        float pred = red[0][r] + red[1][r] + red[2][r] + red[3][r] + b3[0];
        int i = i0 + (r >> 3), j = j0 + (r & 7);
        if (i < 300 && j < 300) {
            int base = b * 90000 + i * 300 + j;
            #pragma unroll
            for (int lo = 0; lo < 6; ++lo) out[lo * 180000 + base] = pred;
        }
    }
}

// ---------------------------------------------------------------------------
extern "C" void kernel_launch(void* const* d_in, const int* in_sizes, int n_in,
                              void* d_out, int out_size, void* d_ws, size_t ws_size,
                              hipStream_t stream) {
    (void)in_sizes; (void)n_in; (void)out_size; (void)ws_size;
    const float* hs   = (const float*)d_in[0];
    const float* Wq   = (const float*)d_in[1];
    const float* bq   = (const float*)d_in[2];
    const float* Wk   = (const float*)d_in[3];
    const float* bk   = (const float*)d_in[4];
    const float* Wsub = (const float*)d_in[5];
    const float* bsub = (const float*)d_in[6];
    const float* Wobj = (const float*)d_in[7];
    const float* bobj = (const float*)d_in[8];
    const float* Wg   = (const float*)d_in[9];
    const float* bg   = (const float*)d_in[10];
    const float* W1   = (const float*)d_in[11];
    const float* b1   = (const float*)d_in[12];
    const float* W2   = (const float*)d_in[13];
    const float* b2   = (const float*)d_in[14];
    const float* W3   = (const float*)d_in[15];
    const float* b3   = (const float*)d_in[16];

    char* ws = (char*)d_ws;
    float* QA   = (float*)ws;            // 1,075,200 f
    float* KA   = QA + 1075200;          // 1,075,200 f
    float* g_ws = KA + 1075200;          // 8,400 f
    float* Pws  = g_ws + 8400;           // 2,150,400 f  (PQ | PK planes)
    // total ws use: 17,236,800 bytes

    k_proj_f32<<<280, 256, 0, stream>>>(hs, Wq, bq, Wk, bk, Wsub, bsub,
                                        Wobj, bobj, QA, KA);
    k_gqk<<<2100, 256, 0, stream>>>(QA, KA, Wg, g_ws);
    k_pq_f32<<<280, 256, 0, stream>>>(QA, KA, W1, Pws);
    k_fused_f32<<<2888, 256, 0, stream>>>(Pws, g_ws, b1, W2, b2, W3, b3, bg,
                                          (float*)d_out);
}

// Round 4
// 496.407 us; speedup vs baseline: 2.5656x; 2.5656x over previous
//
#include <hip/hip_runtime.h>

// ---------------------------------------------------------------------------
// CustomDeformableDetrMLPPredictionHead — MI355X (gfx950), round 3.
// Verified-fp32 skeleton (round 2 passed, absmax 4.9e-4) + MFMA in k_fused:
//   x1 = relu( G(64x112-sparse) @ [PQ;PK](112x256) + b1 )   <- f16 MFMA
//   x2 = relu( x1 @ W2 + b2 )                               <- f16 MFMA
//   pred = x2 @ W3 + b3                                     <- fp32
// G's A-fragments are built in registers (one gate per k-octet), so the
// x1-build costs 64 MFMA/wave instead of ~1400 VALU ops/thread.
// proj/pq/gqk stay fp32 (verified); pq writes f16 [b][it][n][l*8+io] tiles.
// ---------------------------------------------------------------------------

typedef _Float16 half8 __attribute__((ext_vector_type(8)));
typedef float floatx4 __attribute__((ext_vector_type(4)));

#define MFMA16(a, b, c) __builtin_amdgcn_mfma_f32_16x16x32_f16((a), (b), (c), 0, 0, 0)

// ---------------- k_wprep2: W2 -> MFMA-B f16 tiles -------------------------
// 128 tiles (nb 0..15, kb 0..7): lane L holds n=nb*16+(L&15), k=kb*32+(L>>4)*8..+8
__global__ __launch_bounds__(256) void k_wprep2(
    const float* __restrict__ W2, _Float16* __restrict__ W2T)
{
    int eid = blockIdx.x * 256 + threadIdx.x;   // 0..8191
    int tileid = eid >> 6;
    int lane = eid & 63;
    int nb = tileid >> 3, kb = tileid & 7;
    int n = nb * 16 + (lane & 15);
    int k = kb * 32 + (lane >> 4) * 8;
    half8 h;
    #pragma unroll
    for (int j = 0; j < 8; ++j) h[j] = (_Float16)W2[(k + j) * 256 + n];
    *(half8*)(W2T + tileid * 512 + lane * 8) = h;
}

// ---------------- k_proj_f32 ----------------------------------------------
// grid 532 = 28 sub-gemms x 19 row-tiles of 16.  fp32 (verified).
__global__ __launch_bounds__(256) void k_proj_f32(
    const float* __restrict__ hs,
    const float* __restrict__ Wq, const float* __restrict__ bq,
    const float* __restrict__ Wk, const float* __restrict__ bk,
    const float* __restrict__ Wsub, const float* __restrict__ bsub,
    const float* __restrict__ Wobj, const float* __restrict__ bobj,
    float* __restrict__ QA, float* __restrict__ KA)
{
    __shared__ float hsT[256][18];
    int bid = blockIdx.x;
    int s = bid / 19, rt = bid - s * 19;
    int m0 = rt * 16;
    int qk = s & 1, rr = s >> 1;
    int l = rr % 7, b = rr / 7;
    int hs_l = (l < 6) ? l : 5;
    const float* src = hs + (hs_l * 2 + b) * 76800;
    const float* W; const float* bias;
    if (l < 6) { W = (qk ? Wk : Wq) + l * 65536; bias = (qk ? bk : bq) + l * 256; }
    else       { W = qk ? Wobj : Wsub; bias = qk ? bobj : bsub; }
    float* dst = (qk ? KA : QA) + (l * 2 + b) * 76800;

    int t = threadIdx.x;
    #pragma unroll
    for (int r = 0; r < 16; ++r) {
        int m = m0 + r; if (m > 299) m = 299;
        hsT[t][r] = src[m * 256 + t];
    }
    __syncthreads();

    int lane = t & 63, q = t >> 6;
    int ri = lane >> 2, ci = lane & 3;
    int c0 = q * 64 + ci * 16;
    float acc[16] = {};
    for (int d = 0; d < 256; ++d) {
        float a0 = hsT[d][ri];
        const float* wp = W + d * 256 + c0;
        float4 w0 = *(const float4*)(wp + 0);
        float4 w1 = *(const float4*)(wp + 4);
        float4 w2 = *(const float4*)(wp + 8);
        float4 w3 = *(const float4*)(wp + 12);
        float wv[16] = {w0.x, w0.y, w0.z, w0.w, w1.x, w1.y, w1.z, w1.w,
                        w2.x, w2.y, w2.z, w2.w, w3.x, w3.y, w3.z, w3.w};
        #pragma unroll
        for (int cc = 0; cc < 16; ++cc) acc[cc] += a0 * wv[cc];
    }
    int m = m0 + ri;
    if (m < 300) {
        #pragma unroll
        for (int cc = 0; cc < 16; ++cc)
            dst[m * 256 + c0 + cc] = acc[cc] + bias[c0 + cc];
    }
}

// ---------------- k_gqk (verified) ----------------------------------------
__global__ __launch_bounds__(256) void k_gqk(
    const float* __restrict__ QA, const float* __restrict__ KA,
    const float* __restrict__ Wg, float* __restrict__ g_ws)
{
    int gid = blockIdx.x * 4 + (threadIdx.x >> 6);
    int lane = threadIdx.x & 63;
    int qk = gid / 4200, rid = gid - qk * 4200;
    const float* row = (qk ? KA : QA) + rid * 256 + lane * 4;
    const float* w = Wg + qk * 256 + lane * 4;
    float4 a = *(const float4*)row;
    float4 wv = *(const float4*)w;
    float sum = a.x * wv.x + a.y * wv.y + a.z * wv.z + a.w * wv.w;
    #pragma unroll
    for (int off = 1; off < 64; off <<= 1) sum += __shfl_xor(sum, off);
    if (lane == 0) g_ws[gid] = sum;
}

// ---------------- k_pq ----------------------------------------------------
// grid 532.  fp32 GEMM (verified structure), stores f16 transposed tiles:
//   PQt/PKt[b][it][n][l*8+io]  (stride 56 halves; it = i>>3, io = i&7)
__global__ __launch_bounds__(256) void k_pq(
    const float* __restrict__ QA, const float* __restrict__ KA,
    const float* __restrict__ W1, _Float16* __restrict__ PQt,
    _Float16* __restrict__ PKt)
{
    __shared__ float xT[256][18];
    int bid = blockIdx.x;
    int s = bid / 19, rt = bid - s * 19;
    int m0 = rt * 16;
    int qk = s & 1, rr = s >> 1;
    int l = rr % 7, b = rr / 7;
    const float* src = (qk ? KA : QA) + (l * 2 + b) * 76800;
    const float* W = W1 + qk * 65536;
    _Float16* dstb = qk ? PKt : PQt;

    int t = threadIdx.x;
    #pragma unroll
    for (int r = 0; r < 16; ++r) {
        int m = m0 + r; if (m > 299) m = 299;
        xT[t][r] = src[m * 256 + t];
    }
    __syncthreads();

    int lane = t & 63, q = t >> 6;
    int ri = lane >> 2, ci = lane & 3;
    int c0 = q * 64 + ci * 16;
    float acc[16] = {};
    for (int d = 0; d < 256; ++d) {
        float a0 = xT[d][ri];
        const float* wp = W + d * 256 + c0;
        float4 w0 = *(const float4*)(wp + 0);
        float4 w1 = *(const float4*)(wp + 4);
        float4 w2 = *(const float4*)(wp + 8);
        float4 w3 = *(const float4*)(wp + 12);
        float wv[16] = {w0.x, w0.y, w0.z, w0.w, w1.x, w1.y, w1.z, w1.w,
                        w2.x, w2.y, w2.z, w2.w, w3.x, w3.y, w3.z, w3.w};
        #pragma unroll
        for (int cc = 0; cc < 16; ++cc) acc[cc] += a0 * wv[cc];
    }
    int m = m0 + ri;
    if (m < 300) {
        int it8 = m >> 3, io = m & 7;
        #pragma unroll
        for (int cc = 0; cc < 16; ++cc) {
            int n = c0 + cc;
            dstb[((size_t)(b * 38 + it8) * 256 + n) * 56 + l * 8 + io] =
                (_Float16)acc[cc];
        }
    }
}

// ---------------- k_fused -------------------------------------------------
// grid 2*38*38 = 2888, block 256 (4 waves, N-split 64).
// LDS: union{Pt 36.9KB, X 33.8KB} + gate 1.8KB = 38.7KB -> 4 blocks/CU.
__global__ __launch_bounds__(256, 4) void k_fused(
    const _Float16* __restrict__ PQt, const _Float16* __restrict__ PKt,
    const float* __restrict__ g_ws, const float* __restrict__ b1,
    const _Float16* __restrict__ W2T, const float* __restrict__ b2,
    const float* __restrict__ W3, const float* __restrict__ b3,
    const float* __restrict__ bg, float* __restrict__ out)
{
    union SM {
        _Float16 Pt[256][72];   // [n][k], k = l*8+io (0..55); 56..63 zero pad
        _Float16 X[64][264];    // [row][col]
    };
    __shared__ __align__(16) SM sm;
    __shared__ float gate[7][64];

    int t = threadIdx.x, lane = t & 63, wv = t >> 6;
    int mr = lane & 15, hf = lane >> 4;
    int bid = blockIdx.x;
    int b = bid / 1444, rem = bid - b * 1444;
    int it = rem / 38, jt = rem - it * 38;
    int i0 = it * 8, j0 = jt * 8;

    // ---- gates: gate[l][r], r = (i_off<<3)|j_off (verified) ----
    float bg0 = bg[0];
    for (int task = t; task < 448; task += 256) {
        int l = task >> 6, row = task & 63;
        int i = i0 + (row >> 3); if (i > 299) i = 299;
        int j = j0 + (row & 7);  if (j > 299) j = 299;
        float z = g_ws[l * 600 + b * 300 + i] + g_ws[4200 + l * 600 + b * 300 + j] + bg0;
        gate[l][row] = 1.0f / (1.0f + expf(-z));
    }

    // ---- x1-build: C[64][256] = G @ [PQ;PK], two 64-K passes ----
    floatx4 acc1[4][4];
    #pragma unroll
    for (int i = 0; i < 4; ++i)
        #pragma unroll
        for (int j = 0; j < 4; ++j) acc1[i][j] = floatx4{0.f, 0.f, 0.f, 0.f};

    for (int pass = 0; pass < 2; ++pass) {
        const _Float16* src = pass ? PKt : PQt;
        int tb = pass ? jt : it;
        const _Float16* gp = src + ((size_t)(b * 38 + tb) * 256 + t) * 56;
        __syncthreads();   // previous pass's Pt reads done (no-op for pass 0)
        #pragma unroll
        for (int l = 0; l < 7; ++l)
            *(half8*)&sm.Pt[t][l * 8] = *(const half8*)(gp + l * 8);
        *(half8*)&sm.Pt[t][56] = half8{};   // zero pad (keeps 0*x finite)
        __syncthreads();   // staging + gates visible

        #pragma unroll
        for (int ktl = 0; ktl < 2; ++ktl) {
            int l = ktl * 4 + hf;            // source layer for this k-octet
            half8 afr[4];
            #pragma unroll
            for (int mt = 0; mt < 4; ++mt) {
                int r = mt * 16 + mr;
                float g = (l < 7) ? gate[l][r] : 0.f;
                _Float16 gh = (_Float16)g;
                int jstar = pass ? (r & 7) : (r >> 3);
                half8 f;
                #pragma unroll
                for (int j = 0; j < 8; ++j)
                    f[j] = (j == jstar) ? gh : (_Float16)0.f;
                afr[mt] = f;
            }
            #pragma unroll
            for (int nt = 0; nt < 4; ++nt) {
                half8 bfr = *(const half8*)&sm.Pt[wv * 64 + nt * 16 + mr][ktl * 32 + hf * 8];
                #pragma unroll
                for (int mt = 0; mt < 4; ++mt)
                    acc1[mt][nt] = MFMA16(afr[mt], bfr, acc1[mt][nt]);
            }
        }
    }
    __syncthreads();   // all Pt reads done before X overwrites the union

    // ---- epilogue 1: relu(acc1 + b1) -> X (f16) ----
    #pragma unroll
    for (int nt = 0; nt < 4; ++nt) {
        int col = wv * 64 + nt * 16 + mr;
        float bb = b1[col];
        #pragma unroll
        for (int mt = 0; mt < 4; ++mt)
            #pragma unroll
            for (int r = 0; r < 4; ++r) {
                float v = acc1[mt][nt][r] + bb;
                v = v > 0.f ? v : 0.f;
                sm.X[mt * 16 + hf * 4 + r][col] = (_Float16)v;
            }
    }
    __syncthreads();

    // ---- layer 2: (64x256) @ (256x256) f16 MFMA, W2T streamed from L2 ----
    floatx4 acc2[4][4];
    #pragma unroll
    for (int i = 0; i < 4; ++i)
        #pragma unroll
        for (int j = 0; j < 4; ++j) acc2[i][j] = floatx4{0.f, 0.f, 0.f, 0.f};
    for (int s = 0; s < 8; ++s) {
        half8 afr[4];
        #pragma unroll
        for (int mt = 0; mt < 4; ++mt)
            afr[mt] = *(const half8*)&sm.X[mt * 16 + mr][s * 32 + hf * 8];
        #pragma unroll
        for (int nt = 0; nt < 4; ++nt) {
            half8 bfr = *(const half8*)(W2T + (((wv * 4 + nt) * 8 + s) << 9) + lane * 8);
            #pragma unroll
            for (int mt = 0; mt < 4; ++mt)
                acc2[mt][nt] = MFMA16(afr[mt], bfr, acc2[mt][nt]);
        }
    }
    __syncthreads();   // X reads done before overwrite

    // ---- epilogue 2: relu(acc2 + b2) -> X ----
    #pragma unroll
    for (int nt = 0; nt < 4; ++nt) {
        int col = wv * 64 + nt * 16 + mr;
        float bb = b2[col];
        #pragma unroll
        for (int mt = 0; mt < 4; ++mt)
            #pragma unroll
            for (int r = 0; r < 4; ++r) {
                float v = acc2[mt][nt][r] + bb;
                v = v > 0.f ? v : 0.f;
                sm.X[mt * 16 + hf * 4 + r][col] = (_Float16)v;
            }
    }
    __syncthreads();

    // ---- layer 3: pred = x2 @ W3 + b3 (fp32), 6 broadcast copies ----
    {
        int r = t >> 2, qd = t & 3;
        float sum = 0.f;
        #pragma unroll
        for (int dd = 0; dd < 64; dd += 8) {
            half8 xv = *(const half8*)&sm.X[r][qd * 64 + dd];
            float4 w0 = *(const float4*)(W3 + qd * 64 + dd);
            float4 w1 = *(const float4*)(W3 + qd * 64 + dd + 4);
            sum += (float)xv[0] * w0.x + (float)xv[1] * w0.y
                 + (float)xv[2] * w0.z + (float)xv[3] * w0.w
                 + (float)xv[4] * w1.x + (float)xv[5] * w1.y
                 + (float)xv[6] * w1.z + (float)xv[7] * w1.w;
        }
        sum += __shfl_xor(sum, 1);
        sum += __shfl_xor(sum, 2);
        if (qd == 0) {
            int i = i0 + (r >> 3), j = j0 + (r & 7);
            if (i < 300 && j < 300) {
                float pred = sum + b3[0];
                int base = b * 90000 + i * 300 + j;
                #pragma unroll
                for (int lo = 0; lo < 6; ++lo) out[lo * 180000 + base] = pred;
            }
        }
    }
}

// ---------------------------------------------------------------------------
extern "C" void kernel_launch(void* const* d_in, const int* in_sizes, int n_in,
                              void* d_out, int out_size, void* d_ws, size_t ws_size,
                              hipStream_t stream) {
    (void)in_sizes; (void)n_in; (void)out_size; (void)ws_size;
    const float* hs   = (const float*)d_in[0];
    const float* Wq   = (const float*)d_in[1];
    const float* bq   = (const float*)d_in[2];
    const float* Wk   = (const float*)d_in[3];
    const float* bk   = (const float*)d_in[4];
    const float* Wsub = (const float*)d_in[5];
    const float* bsub = (const float*)d_in[6];
    const float* Wobj = (const float*)d_in[7];
    const float* bobj = (const float*)d_in[8];
    const float* Wg   = (const float*)d_in[9];
    const float* bg   = (const float*)d_in[10];
    const float* W1   = (const float*)d_in[11];
    const float* b1   = (const float*)d_in[12];
    const float* W2   = (const float*)d_in[13];
    const float* b2   = (const float*)d_in[14];
    const float* W3   = (const float*)d_in[15];
    const float* b3   = (const float*)d_in[16];

    char* ws = (char*)d_ws;
    float* QA   = (float*)ws;                    // 1,075,200 f
    float* KA   = QA + 1075200;                  // 1,075,200 f
    float* g_ws = KA + 1075200;                  // 8,400 f
    _Float16* PQt = (_Float16*)(g_ws + 8400);    // 2*38*256*56 = 1,089,536 h
    _Float16* PKt = PQt + 1089536;               // 1,089,536 h
    _Float16* W2T = PKt + 1089536;               // 65,536 h
    // total ws use: ~13.1 MB

    k_wprep2<<<32, 256, 0, stream>>>(W2, W2T);
    k_proj_f32<<<532, 256, 0, stream>>>(hs, Wq, bq, Wk, bk, Wsub, bsub,
                                        Wobj, bobj, QA, KA);
    k_gqk<<<2100, 256, 0, stream>>>(QA, KA, Wg, g_ws);
    k_pq<<<532, 256, 0, stream>>>(QA, KA, W1, PQt, PKt);
    k_fused<<<2888, 256, 0, stream>>>(PQt, PKt, g_ws, b1, W2T, b2, W3, b3, bg,
                                      (float*)d_out);
}

// Round 5
// 177.534 us; speedup vs baseline: 7.1737x; 2.7961x over previous
//
#include <hip/hip_runtime.h>

// ---------------------------------------------------------------------------
// CustomDeformableDetrMLPPredictionHead — MI355X (gfx950), round 4.
// All GEMMs on f16 MFMA using the round-3-verified patterns.
//   k_wprep  : pack 17 256x256 fp32 weight mats -> MFMA-B f16 tiles
//              (Wq[6], Wk[6], Wsub, Wobj, W1a, W1b, W2)
//   k_projpq : per 64-row tile: stage hs->f16 LDS; GEMM1 = hs@Wproj (+bias)
//              -> Q-tile f16 LDS; inline gq/gk row-dots -> g_ws;
//              GEMM2 = Q@W1half -> PQt/PKt f16 transposed tiles.
//   k_fused  : (verbatim round 3, verified) gates -> x1 = G@[PQ;PK] sparse
//              MFMA -> relu -> x2 = x1@W2 MFMA -> relu -> layer3 fp32 dot.
// ---------------------------------------------------------------------------

typedef _Float16 half8 __attribute__((ext_vector_type(8)));
typedef float floatx4 __attribute__((ext_vector_type(4)));

#define MFMA16(a, b, c) __builtin_amdgcn_mfma_f32_16x16x32_f16((a), (b), (c), 0, 0, 0)

// ---------------- k_wprep: 17 mats -> MFMA-B f16 tiles ---------------------
// per mat: tiles (nb 0..15, kb 0..7), tileid = nb*8+kb, 512 f16 lane-major;
// lane L holds n = nb*16+(L&15), k = kb*32+(L>>4)*8 .. +8   (verified r3)
__global__ __launch_bounds__(256) void k_wprep(
    const float* __restrict__ Wq, const float* __restrict__ Wk,
    const float* __restrict__ Wsub, const float* __restrict__ Wobj,
    const float* __restrict__ W1, const float* __restrict__ W2,
    _Float16* __restrict__ WT)
{
    int eid = blockIdx.x * 256 + threadIdx.x;     // 0..139263
    int mat = eid >> 13;                          // 0..16
    int rem = eid & 8191;
    int tileid = rem >> 6;
    int lane = rem & 63;
    const float* src;
    if      (mat < 6)  src = Wq + mat * 65536;
    else if (mat < 12) src = Wk + (mat - 6) * 65536;
    else if (mat == 12) src = Wsub;
    else if (mat == 13) src = Wobj;
    else if (mat == 14) src = W1;            // W1a: rows 0..255
    else if (mat == 15) src = W1 + 65536;    // W1b: rows 256..511
    else               src = W2;
    int nb = tileid >> 3, kb = tileid & 7;
    int n = nb * 16 + (lane & 15);
    int k = kb * 32 + (lane >> 4) * 8;
    half8 h;
    #pragma unroll
    for (int j = 0; j < 8; ++j) h[j] = (_Float16)src[(k + j) * 256 + n];
    *(half8*)(WT + mat * 65536 + tileid * 512 + lane * 8) = h;
}

// ---------------- k_projpq ------------------------------------------------
// grid 140 = 28 sub-problems x 5 M-tiles of 64.  block 256 (4 waves, N=64 ea).
// LDS: Ah 33.8KB + X 33.8KB = 67.6KB.
__global__ __launch_bounds__(256) void k_projpq(
    const float* __restrict__ hs, const _Float16* __restrict__ WT,
    const float* __restrict__ bq, const float* __restrict__ bk,
    const float* __restrict__ bsub, const float* __restrict__ bobj,
    const float* __restrict__ Wg,
    _Float16* __restrict__ PQt, _Float16* __restrict__ PKt,
    float* __restrict__ g_ws)
{
    __shared__ __align__(16) _Float16 Ah[64][264];
    __shared__ __align__(16) _Float16 X[64][264];

    int bid = blockIdx.x;
    int s = bid / 5, mt5 = bid - s * 5;
    int qk = s & 1, rr = s >> 1;
    int l = rr % 7, b = rr / 7;
    int hs_l = (l < 6) ? l : 5;
    const float* src = hs + (hs_l * 2 + b) * 76800;
    int projmat = (l < 6) ? (qk * 6 + l) : (12 + qk);
    const _Float16* WprojT = WT + projmat * 65536;
    const _Float16* W1hT   = WT + (14 + qk) * 65536;
    const float* bias = (l < 6) ? ((qk ? bk : bq) + l * 256) : (qk ? bobj : bsub);
    _Float16* dstP = qk ? PKt : PQt;
    const float* wvec = Wg + qk * 256;
    float* gdst = g_ws + qk * 4200 + (l * 2 + b) * 300;
    int m0 = mt5 * 64;

    int t = threadIdx.x, lane = t & 63, wv = t >> 6;
    int mr = lane & 15, hf = lane >> 4;

    // ---- stage hs rows -> Ah (f16).  4 threads/row, 64 cols each ----
    {
        int row = t >> 2, qt = t & 3;
        int m = m0 + row; if (m > 299) m = 299;   // clamp; stores masked later
        const float* p = src + m * 256 + qt * 64;
        #pragma unroll
        for (int i = 0; i < 16; ++i) {
            float4 v = *(const float4*)(p + 4 * i);
            _Float16* d = &Ah[row][qt * 64 + 4 * i];
            d[0] = (_Float16)v.x; d[1] = (_Float16)v.y;
            d[2] = (_Float16)v.z; d[3] = (_Float16)v.w;
        }
    }
    __syncthreads();

    // ---- GEMM1: Q = hs @ Wproj  (verified layer-2 pattern) ----
    floatx4 acc[4][4];
    #pragma unroll
    for (int i = 0; i < 4; ++i)
        #pragma unroll
        for (int j = 0; j < 4; ++j) acc[i][j] = floatx4{0.f, 0.f, 0.f, 0.f};
    for (int ks = 0; ks < 8; ++ks) {
        half8 afr[4];
        #pragma unroll
        for (int mt = 0; mt < 4; ++mt)
            afr[mt] = *(const half8*)&Ah[mt * 16 + mr][ks * 32 + hf * 8];
        #pragma unroll
        for (int nt = 0; nt < 4; ++nt) {
            half8 bfr = *(const half8*)(WprojT + (((wv * 4 + nt) * 8 + ks) << 9) + lane * 8);
            #pragma unroll
            for (int mt = 0; mt < 4; ++mt)
                acc[mt][nt] = MFMA16(afr[mt], bfr, acc[mt][nt]);
        }
    }

    // ---- epilogue 1: Q + bias -> X (f16)  (verified C-layout) ----
    #pragma unroll
    for (int nt = 0; nt < 4; ++nt) {
        int col = wv * 64 + nt * 16 + mr;
        float bb = bias[col];
        #pragma unroll
        for (int mt = 0; mt < 4; ++mt)
            #pragma unroll
            for (int r = 0; r < 4; ++r)
                X[mt * 16 + hf * 4 + r][col] = (_Float16)(acc[mt][nt][r] + bb);
    }
    __syncthreads();

    // ---- gq/gk: row dots with wvec -> g_ws ----
    {
        int row = t >> 2, qt = t & 3;
        float sum = 0.f;
        #pragma unroll
        for (int i = 0; i < 64; i += 8) {
            half8 xv = *(const half8*)&X[row][qt * 64 + i];
            const float* wp = wvec + qt * 64 + i;
            float4 w0 = *(const float4*)wp;
            float4 w1 = *(const float4*)(wp + 4);
            sum += (float)xv[0] * w0.x + (float)xv[1] * w0.y
                 + (float)xv[2] * w0.z + (float)xv[3] * w0.w
                 + (float)xv[4] * w1.x + (float)xv[5] * w1.y
                 + (float)xv[6] * w1.z + (float)xv[7] * w1.w;
        }
        sum += __shfl_xor(sum, 1);
        sum += __shfl_xor(sum, 2);
        int m = m0 + row;
        if (qt == 0 && m < 300) gdst[m] = sum;
    }

    // ---- GEMM2: P = Q @ W1half ----
    floatx4 acc2[4][4];
    #pragma unroll
    for (int i = 0; i < 4; ++i)
        #pragma unroll
        for (int j = 0; j < 4; ++j) acc2[i][j] = floatx4{0.f, 0.f, 0.f, 0.f};
    for (int ks = 0; ks < 8; ++ks) {
        half8 afr[4];
        #pragma unroll
        for (int mt = 0; mt < 4; ++mt)
            afr[mt] = *(const half8*)&X[mt * 16 + mr][ks * 32 + hf * 8];
        #pragma unroll
        for (int nt = 0; nt < 4; ++nt) {
            half8 bfr = *(const half8*)(W1hT + (((wv * 4 + nt) * 8 + ks) << 9) + lane * 8);
            #pragma unroll
            for (int mt = 0; mt < 4; ++mt)
                acc2[mt][nt] = MFMA16(afr[mt], bfr, acc2[mt][nt]);
        }
    }

    // ---- epilogue 2: P -> PQt/PKt f16 transposed tiles (verified layout) ----
    // dst[((b*38 + m>>3)*256 + n)*56 + l*8 + (m&7)]
    #pragma unroll
    for (int nt = 0; nt < 4; ++nt) {
        int n = wv * 64 + nt * 16 + mr;
        #pragma unroll
        for (int mt = 0; mt < 4; ++mt)
            #pragma unroll
            for (int r = 0; r < 4; ++r) {
                int m = m0 + mt * 16 + hf * 4 + r;
                if (m < 300)
                    dstP[((size_t)(b * 38 + (m >> 3)) * 256 + n) * 56 + l * 8 + (m & 7)] =
                        (_Float16)acc2[mt][nt][r];
            }
    }
}

// ---------------- k_fused (verbatim round 3, verified) ---------------------
// grid 2*38*38 = 2888, block 256 (4 waves, N-split 64).
// LDS: union{Pt 36.9KB, X 33.8KB} + gate 1.8KB = 38.7KB -> 4 blocks/CU.
__global__ __launch_bounds__(256, 4) void k_fused(
    const _Float16* __restrict__ PQt, const _Float16* __restrict__ PKt,
    const float* __restrict__ g_ws, const float* __restrict__ b1,
    const _Float16* __restrict__ W2T, const float* __restrict__ b2,
    const float* __restrict__ W3, const float* __restrict__ b3,
    const float* __restrict__ bg, float* __restrict__ out)
{
    union SM {
        _Float16 Pt[256][72];   // [n][k], k = l*8+io (0..55); 56..63 zero pad
        _Float16 X[64][264];    // [row][col]
    };
    __shared__ __align__(16) SM sm;
    __shared__ float gate[7][64];

    int t = threadIdx.x, lane = t & 63, wv = t >> 6;
    int mr = lane & 15, hf = lane >> 4;
    int bid = blockIdx.x;
    int b = bid / 1444, rem = bid - b * 1444;
    int it = rem / 38, jt = rem - it * 38;
    int i0 = it * 8, j0 = jt * 8;

    // ---- gates: gate[l][r], r = (i_off<<3)|j_off (verified) ----
    float bg0 = bg[0];
    for (int task = t; task < 448; task += 256) {
        int l = task >> 6, row = task & 63;
        int i = i0 + (row >> 3); if (i > 299) i = 299;
        int j = j0 + (row & 7);  if (j > 299) j = 299;
        float z = g_ws[l * 600 + b * 300 + i] + g_ws[4200 + l * 600 + b * 300 + j] + bg0;
        gate[l][row] = 1.0f / (1.0f + expf(-z));
    }

    // ---- x1-build: C[64][256] = G @ [PQ;PK], two 64-K passes ----
    floatx4 acc1[4][4];
    #pragma unroll
    for (int i = 0; i < 4; ++i)
        #pragma unroll
        for (int j = 0; j < 4; ++j) acc1[i][j] = floatx4{0.f, 0.f, 0.f, 0.f};

    for (int pass = 0; pass < 2; ++pass) {
        const _Float16* src = pass ? PKt : PQt;
        int tb = pass ? jt : it;
        const _Float16* gp = src + ((size_t)(b * 38 + tb) * 256 + t) * 56;
        __syncthreads();   // previous pass's Pt reads done (no-op for pass 0)
        #pragma unroll
        for (int l = 0; l < 7; ++l)
            *(half8*)&sm.Pt[t][l * 8] = *(const half8*)(gp + l * 8);
        *(half8*)&sm.Pt[t][56] = half8{};   // zero pad
        __syncthreads();   // staging + gates visible

        #pragma unroll
        for (int ktl = 0; ktl < 2; ++ktl) {
            int l = ktl * 4 + hf;            // source layer for this k-octet
            half8 afr[4];
            #pragma unroll
            for (int mt = 0; mt < 4; ++mt) {
                int r = mt * 16 + mr;
                float g = (l < 7) ? gate[l][r] : 0.f;
                _Float16 gh = (_Float16)g;
                int jstar = pass ? (r & 7) : (r >> 3);
                half8 f;
                #pragma unroll
                for (int j = 0; j < 8; ++j)
                    f[j] = (j == jstar) ? gh : (_Float16)0.f;
                afr[mt] = f;
            }
            #pragma unroll
            for (int nt = 0; nt < 4; ++nt) {
                half8 bfr = *(const half8*)&sm.Pt[wv * 64 + nt * 16 + mr][ktl * 32 + hf * 8];
                #pragma unroll
                for (int mt = 0; mt < 4; ++mt)
                    acc1[mt][nt] = MFMA16(afr[mt], bfr, acc1[mt][nt]);
            }
        }
    }
    __syncthreads();   // all Pt reads done before X overwrites the union

    // ---- epilogue 1: relu(acc1 + b1) -> X (f16) ----
    #pragma unroll
    for (int nt = 0; nt < 4; ++nt) {
        int col = wv * 64 + nt * 16 + mr;
        float bb = b1[col];
        #pragma unroll
        for (int mt = 0; mt < 4; ++mt)
            #pragma unroll
            for (int r = 0; r < 4; ++r) {
                float v = acc1[mt][nt][r] + bb;
                v = v > 0.f ? v : 0.f;
                sm.X[mt * 16 + hf * 4 + r][col] = (_Float16)v;
            }
    }
    __syncthreads();

    // ---- layer 2: (64x256) @ (256x256) f16 MFMA ----
    floatx4 acc2[4][4];
    #pragma unroll
    for (int i = 0; i < 4; ++i)
        #pragma unroll
        for (int j = 0; j < 4; ++j) acc2[i][j] = floatx4{0.f, 0.f, 0.f, 0.f};
    for (int s = 0; s < 8; ++s) {
        half8 afr[4];
        #pragma unroll
        for (int mt = 0; mt < 4; ++mt)
            afr[mt] = *(const half8*)&sm.X[mt * 16 + mr][s * 32 + hf * 8];
        #pragma unroll
        for (int nt = 0; nt < 4; ++nt) {
            half8 bfr = *(const half8*)(W2T + (((wv * 4 + nt) * 8 + s) << 9) + lane * 8);
            #pragma unroll
            for (int mt = 0; mt < 4; ++mt)
                acc2[mt][nt] = MFMA16(afr[mt], bfr, acc2[mt][nt]);
        }
    }
    __syncthreads();   // X reads done before overwrite

    // ---- epilogue 2: relu(acc2 + b2) -> X ----
    #pragma unroll
    for (int nt = 0; nt < 4; ++nt) {
        int col = wv * 64 + nt * 16 + mr;
        float bb = b2[col];
        #pragma unroll
        for (int mt = 0; mt < 4; ++mt)
            #pragma unroll
            for (int r = 0; r < 4; ++r) {
                float v = acc2[mt][nt][r] + bb;
                v = v > 0.f ? v : 0.f;
                sm.X[mt * 16 + hf * 4 + r][col] = (_Float16)v;
            }
    }
    __syncthreads();

    // ---- layer 3: pred = x2 @ W3 + b3 (fp32), 6 broadcast copies ----
    {
        int r = t >> 2, qd = t & 3;
        float sum = 0.f;
        #pragma unroll
        for (int dd = 0; dd < 64; dd += 8) {
            half8 xv = *(const half8*)&sm.X[r][qd * 64 + dd];
            float4 w0 = *(const float4*)(W3 + qd * 64 + dd);
            float4 w1 = *(const float4*)(W3 + qd * 64 + dd + 4);
            sum += (float)xv[0] * w0.x + (float)xv[1] * w0.y
                 + (float)xv[2] * w0.z + (float)xv[3] * w0.w
                 + (float)xv[4] * w1.x + (float)xv[5] * w1.y
                 + (float)xv[6] * w1.z + (float)xv[7] * w1.w;
        }
        sum += __shfl_xor(sum, 1);
        sum += __shfl_xor(sum, 2);
        if (qd == 0) {
            int i = i0 + (r >> 3), j = j0 + (r & 7);
            if (i < 300 && j < 300) {
                float pred = sum + b3[0];
                int base = b * 90000 + i * 300 + j;
                #pragma unroll
                for (int lo = 0; lo < 6; ++lo) out[lo * 180000 + base] = pred;
            }
        }
    }
}

// ---------------------------------------------------------------------------
extern "C" void kernel_launch(void* const* d_in, const int* in_sizes, int n_in,
                              void* d_out, int out_size, void* d_ws, size_t ws_size,
                              hipStream_t stream) {
    (void)in_sizes; (void)n_in; (void)out_size; (void)ws_size;
    const float* hs   = (const float*)d_in[0];
    const float* Wq   = (const float*)d_in[1];
    const float* bq   = (const float*)d_in[2];
    const float* Wk   = (const float*)d_in[3];
    const float* bk   = (const float*)d_in[4];
    const float* Wsub = (const float*)d_in[5];
    const float* bsub = (const float*)d_in[6];
    const float* Wobj = (const float*)d_in[7];
    const float* bobj = (const float*)d_in[8];
    const float* Wg   = (const float*)d_in[9];
    const float* bg   = (const float*)d_in[10];
    const float* W1   = (const float*)d_in[11];
    const float* b1   = (const float*)d_in[12];
    const float* W2   = (const float*)d_in[13];
    const float* b2   = (const float*)d_in[14];
    const float* W3   = (const float*)d_in[15];
    const float* b3   = (const float*)d_in[16];

    char* ws = (char*)d_ws;
    float* g_ws   = (float*)ws;                  // 8,400 f
    _Float16* WT  = (_Float16*)(ws + 33600);     // 17*65536 h  (2.23 MB)
    _Float16* PQt = WT + 17 * 65536;             // 2*38*256*56 = 1,089,536 h
    _Float16* PKt = PQt + 1089536;               // 1,089,536 h
    // total ws use: ~6.7 MB

    k_wprep<<<544, 256, 0, stream>>>(Wq, Wk, Wsub, Wobj, W1, W2, WT);
    k_projpq<<<140, 256, 0, stream>>>(hs, WT, bq, bk, bsub, bobj, Wg,
                                      PQt, PKt, g_ws);
    k_fused<<<2888, 256, 0, stream>>>(PQt, PKt, g_ws, b1, WT + 16 * 65536,
                                      b2, W3, b3, bg, (float*)d_out);
}

// Round 6
// 168.305 us; speedup vs baseline: 7.5671x; 1.0548x over previous
//
#include <hip/hip_runtime.h>

// ---------------------------------------------------------------------------
// CustomDeformableDetrMLPPredictionHead — MI355X (gfx950), round 5.
// Both fused GEMMs computed TRANSPOSED (x^T = W^T @ a^T): packed weight
// tiles act as A-fragments (same lane math as verified B-packing), LDS
// activations act as B-fragments (same reads as before), and the MFMA D
// layout then hands each lane 4 CONSECUTIVE output columns -> all epilogues
// are packed b64 LDS writes (kills the 2.86M bank conflicts of round 4).
// k_projpq: M-tile 32 (grid 280, full CU coverage) + PQt/PKt stores staged
// through LDS and emitted as coalesced 16B half8 stores.
// ---------------------------------------------------------------------------

typedef _Float16 half8 __attribute__((ext_vector_type(8)));
typedef _Float16 half4v __attribute__((ext_vector_type(4)));
typedef float floatx4 __attribute__((ext_vector_type(4)));

#define MFMA16(a, b, c) __builtin_amdgcn_mfma_f32_16x16x32_f16((a), (b), (c), 0, 0, 0)

// ---------------- k_wprep: 17 mats -> MFMA f16 tiles (verified r3/r4) ------
// per mat: tiles (nb 0..15, kb 0..7), tileid = nb*8+kb, 512 f16 lane-major;
// lane L holds idx = nb*16+(L&15), k = kb*32+(L>>4)*8 .. +8
__global__ __launch_bounds__(256) void k_wprep(
    const float* __restrict__ Wq, const float* __restrict__ Wk,
    const float* __restrict__ Wsub, const float* __restrict__ Wobj,
    const float* __restrict__ W1, const float* __restrict__ W2,
    _Float16* __restrict__ WT)
{
    int eid = blockIdx.x * 256 + threadIdx.x;     // 0..139263
    int mat = eid >> 13;                          // 0..16
    int rem = eid & 8191;
    int tileid = rem >> 6;
    int lane = rem & 63;
    const float* src;
    if      (mat < 6)  src = Wq + mat * 65536;
    else if (mat < 12) src = Wk + (mat - 6) * 65536;
    else if (mat == 12) src = Wsub;
    else if (mat == 13) src = Wobj;
    else if (mat == 14) src = W1;            // W1a: rows 0..255
    else if (mat == 15) src = W1 + 65536;    // W1b: rows 256..511
    else               src = W2;
    int nb = tileid >> 3, kb = tileid & 7;
    int n = nb * 16 + (lane & 15);
    int k = kb * 32 + (lane >> 4) * 8;
    half8 h;
    #pragma unroll
    for (int j = 0; j < 8; ++j) h[j] = (_Float16)src[(k + j) * 256 + n];
    *(half8*)(WT + mat * 65536 + tileid * 512 + lane * 8) = h;
}

// ---------------- k_projpq ------------------------------------------------
// grid 280 = 28 sub-problems x 10 M-tiles of 32.  block 256 (4 waves).
// Flipped GEMMs: waves split the 256 OUTPUT cols (64 each); rows 32 = 2 nt.
// LDS: Ah[32][264] 16.9KB + X[32][264] 16.9KB = 33.8KB.
__global__ __launch_bounds__(256) void k_projpq(
    const float* __restrict__ hs, const _Float16* __restrict__ WT,
    const float* __restrict__ bq, const float* __restrict__ bk,
    const float* __restrict__ bsub, const float* __restrict__ bobj,
    const float* __restrict__ Wg,
    _Float16* __restrict__ PQt, _Float16* __restrict__ PKt,
    float* __restrict__ g_ws)
{
    __shared__ __align__(16) _Float16 Ah[32][264];   // hs f16; reused as Pst
    __shared__ __align__(16) _Float16 X[32][264];    // Q f16

    int bid = blockIdx.x;
    int s = bid / 10, rt = bid - s * 10;
    int m0 = rt * 32;
    int qk = s & 1, rr = s >> 1;
    int l = rr % 7, b = rr / 7;
    int hs_l = (l < 6) ? l : 5;
    const float* src = hs + (hs_l * 2 + b) * 76800;
    int projmat = (l < 6) ? (qk * 6 + l) : (12 + qk);
    const _Float16* WprojT = WT + projmat * 65536;
    const _Float16* W1hT   = WT + (14 + qk) * 65536;
    const float* bias = (l < 6) ? ((qk ? bk : bq) + l * 256) : (qk ? bobj : bsub);
    _Float16* dstP = qk ? PKt : PQt;
    const float* wvec = Wg + qk * 256;
    float* gdst = g_ws + qk * 4200 + (l * 2 + b) * 300;

    int t = threadIdx.x, lane = t & 63, wv = t >> 6;
    int mr = lane & 15, hf = lane >> 4;

    // ---- stage hs rows -> Ah (f16).  8 threads/row, 32 cols each ----
    {
        int row = t >> 3, qt = t & 7;
        int m = m0 + row; if (m > 299) m = 299;   // clamp; masked later
        const float* p = src + m * 256 + qt * 32;
        #pragma unroll
        for (int i = 0; i < 8; ++i) {
            float4 v = *(const float4*)(p + 4 * i);
            half4v h;
            h[0] = (_Float16)v.x; h[1] = (_Float16)v.y;
            h[2] = (_Float16)v.z; h[3] = (_Float16)v.w;
            *(half4v*)&Ah[row][qt * 32 + 4 * i] = h;
        }
    }
    __syncthreads();

    // ---- GEMM1 (flipped): Q^T = Wproj^T @ hs^T ----
    floatx4 acc[4][2];
    #pragma unroll
    for (int i = 0; i < 4; ++i)
        #pragma unroll
        for (int j = 0; j < 2; ++j) acc[i][j] = floatx4{0.f, 0.f, 0.f, 0.f};
    for (int ks = 0; ks < 8; ++ks) {
        half8 bfr[2];
        #pragma unroll
        for (int nt = 0; nt < 2; ++nt)
            bfr[nt] = *(const half8*)&Ah[nt * 16 + mr][ks * 32 + hf * 8];
        #pragma unroll
        for (int mt = 0; mt < 4; ++mt) {
            half8 afr = *(const half8*)(WprojT + (((wv * 4 + mt) * 8 + ks) << 9) + lane * 8);
            #pragma unroll
            for (int nt = 0; nt < 2; ++nt)
                acc[mt][nt] = MFMA16(afr, bfr[nt], acc[mt][nt]);
        }
    }

    // ---- epilogue 1: Q + bias -> X[row][qcol], packed b64 ----
    #pragma unroll
    for (int mt = 0; mt < 4; ++mt) {
        int n0 = wv * 64 + mt * 16 + hf * 4;
        float4 bb = *(const float4*)&bias[n0];
        float bv[4] = {bb.x, bb.y, bb.z, bb.w};
        #pragma unroll
        for (int nt = 0; nt < 2; ++nt) {
            int r = nt * 16 + mr;
            half4v h;
            #pragma unroll
            for (int u = 0; u < 4; ++u) h[u] = (_Float16)(acc[mt][nt][u] + bv[u]);
            *(half4v*)&X[r][n0] = h;
        }
    }
    __syncthreads();

    // ---- gq/gk: row dots with wvec -> g_ws ----
    {
        int row = t >> 3, qt = t & 7;
        float sum = 0.f;
        #pragma unroll
        for (int i = 0; i < 32; i += 8) {
            half8 xv = *(const half8*)&X[row][qt * 32 + i];
            const float* wp = wvec + qt * 32 + i;
            float4 w0 = *(const float4*)wp;
            float4 w1 = *(const float4*)(wp + 4);
            sum += (float)xv[0] * w0.x + (float)xv[1] * w0.y
                 + (float)xv[2] * w0.z + (float)xv[3] * w0.w
                 + (float)xv[4] * w1.x + (float)xv[5] * w1.y
                 + (float)xv[6] * w1.z + (float)xv[7] * w1.w;
        }
        sum += __shfl_xor(sum, 1);
        sum += __shfl_xor(sum, 2);
        sum += __shfl_xor(sum, 4);
        int m = m0 + row;
        if (qt == 0 && m < 300) gdst[m] = sum;
    }

    // ---- GEMM2 (flipped): P^T = W1h^T @ Q^T ----
    floatx4 acc2[4][2];
    #pragma unroll
    for (int i = 0; i < 4; ++i)
        #pragma unroll
        for (int j = 0; j < 2; ++j) acc2[i][j] = floatx4{0.f, 0.f, 0.f, 0.f};
    for (int ks = 0; ks < 8; ++ks) {
        half8 bfr[2];
        #pragma unroll
        for (int nt = 0; nt < 2; ++nt)
            bfr[nt] = *(const half8*)&X[nt * 16 + mr][ks * 32 + hf * 8];
        #pragma unroll
        for (int mt = 0; mt < 4; ++mt) {
            half8 afr = *(const half8*)(W1hT + (((wv * 4 + mt) * 8 + ks) << 9) + lane * 8);
            #pragma unroll
            for (int nt = 0; nt < 2; ++nt)
                acc2[mt][nt] = MFMA16(afr, bfr[nt], acc2[mt][nt]);
        }
    }

    // ---- epilogue 2: P -> Pst (reuse Ah), packed b64 ----
    #pragma unroll
    for (int mt = 0; mt < 4; ++mt) {
        int n0 = wv * 64 + mt * 16 + hf * 4;
        #pragma unroll
        for (int nt = 0; nt < 2; ++nt) {
            int r = nt * 16 + mr;
            half4v h;
            #pragma unroll
            for (int u = 0; u < 4; ++u) h[u] = (_Float16)acc2[mt][nt][u];
            *(half4v*)&Ah[r][n0] = h;
        }
    }
    __syncthreads();

    // ---- coalesced store: dst[((b*38+it)*256+n)*56 + l*8 + io], 16B ----
    for (int z = 0; z < 4; ++z) {
        int task = z * 256 + t;            // 0..1023
        int it4 = task >> 8, n = task & 255;
        int it = rt * 4 + it4;
        if (it < 38) {
            half8 h;
            #pragma unroll
            for (int io = 0; io < 8; ++io) h[io] = Ah[it4 * 8 + io][n];
            *(half8*)(dstP + ((size_t)(b * 38 + it) * 256 + n) * 56 + l * 8) = h;
        }
    }
}

// ---------------- k_fused -------------------------------------------------
// grid 2*38*38 = 2888, block 256 (4 waves; waves split 256 out-cols).
// Flipped GEMMs -> all epilogues are packed b64 writes (no bank conflicts).
// LDS: union{Pt 36.9KB, X 33.8KB} + gate 1.8KB = 38.7KB -> 4 blocks/CU.
__global__ __launch_bounds__(256, 4) void k_fused(
    const _Float16* __restrict__ PQt, const _Float16* __restrict__ PKt,
    const float* __restrict__ g_ws, const float* __restrict__ b1,
    const _Float16* __restrict__ W2T, const float* __restrict__ b2,
    const float* __restrict__ W3, const float* __restrict__ b3,
    const float* __restrict__ bg, float* __restrict__ out)
{
    union SM {
        _Float16 Pt[256][72];   // [n][k], k = l*8+io (0..55); 56..63 zero pad
        _Float16 X[64][264];    // [r][col]
    };
    __shared__ __align__(16) SM sm;
    __shared__ float gate[7][64];

    int t = threadIdx.x, lane = t & 63, wv = t >> 6;
    int mr = lane & 15, hf = lane >> 4;
    int bid = blockIdx.x;
    int b = bid / 1444, rem = bid - b * 1444;
    int it = rem / 38, jt = rem - it * 38;
    int i0 = it * 8, j0 = jt * 8;

    // ---- gates: gate[l][r], r = (i_off<<3)|j_off (verified) ----
    float bg0 = bg[0];
    for (int task = t; task < 448; task += 256) {
        int l = task >> 6, row = task & 63;
        int i = i0 + (row >> 3); if (i > 299) i = 299;
        int j = j0 + (row & 7);  if (j > 299) j = 299;
        float z = g_ws[l * 600 + b * 300 + i] + g_ws[4200 + l * 600 + b * 300 + j] + bg0;
        gate[l][row] = 1.0f / (1.0f + expf(-z));
    }

    // ---- x1-build (flipped): x1^T = [PQ;PK]^T @ G^T, two 64-K passes ----
    // A = Pt dense (m = n-col), B = G sparse built in registers (n = r).
    floatx4 acc1[4][4];
    #pragma unroll
    for (int i = 0; i < 4; ++i)
        #pragma unroll
        for (int j = 0; j < 4; ++j) acc1[i][j] = floatx4{0.f, 0.f, 0.f, 0.f};

    for (int pass = 0; pass < 2; ++pass) {
        const _Float16* src = pass ? PKt : PQt;
        int tb = pass ? jt : it;
        const _Float16* gp = src + ((size_t)(b * 38 + tb) * 256 + t) * 56;
        __syncthreads();   // previous pass's Pt reads done (gates for pass 0)
        #pragma unroll
        for (int l = 0; l < 7; ++l)
            *(half8*)&sm.Pt[t][l * 8] = *(const half8*)(gp + l * 8);
        *(half8*)&sm.Pt[t][56] = half8{};   // zero pad
        __syncthreads();   // staging + gates visible

        #pragma unroll
        for (int ktl = 0; ktl < 2; ++ktl) {
            int l = ktl * 4 + hf;            // source layer for this k-octet
            half8 bfr[4];
            #pragma unroll
            for (int nt = 0; nt < 4; ++nt) {
                int r = nt * 16 + mr;
                float g = (l < 7) ? gate[l][r] : 0.f;
                _Float16 gh = (_Float16)g;
                int jstar = pass ? (r & 7) : (r >> 3);
                half8 f;
                #pragma unroll
                for (int j = 0; j < 8; ++j)
                    f[j] = (j == jstar) ? gh : (_Float16)0.f;
                bfr[nt] = f;
            }
            #pragma unroll
            for (int mt = 0; mt < 4; ++mt) {
                half8 afr = *(const half8*)&sm.Pt[wv * 64 + mt * 16 + mr][ktl * 32 + hf * 8];
                #pragma unroll
                for (int nt = 0; nt < 4; ++nt)
                    acc1[mt][nt] = MFMA16(afr, bfr[nt], acc1[mt][nt]);
            }
        }
    }
    __syncthreads();   // all Pt reads done before X overwrites the union

    // ---- epilogue 1: relu(x1 + b1) -> X[r][n], packed b64 ----
    #pragma unroll
    for (int mt = 0; mt < 4; ++mt) {
        int n0 = wv * 64 + mt * 16 + hf * 4;
        float4 bb = *(const float4*)&b1[n0];
        float bv[4] = {bb.x, bb.y, bb.z, bb.w};
        #pragma unroll
        for (int nt = 0; nt < 4; ++nt) {
            int r = nt * 16 + mr;
            half4v h;
            #pragma unroll
            for (int u = 0; u < 4; ++u) {
                float v = acc1[mt][nt][u] + bv[u];
                h[u] = (_Float16)(v > 0.f ? v : 0.f);
            }
            *(half4v*)&sm.X[r][n0] = h;
        }
    }
    __syncthreads();

    // ---- layer 2 (flipped): x2^T = W2^T @ x1^T ----
    floatx4 acc2[4][4];
    #pragma unroll
    for (int i = 0; i < 4; ++i)
        #pragma unroll
        for (int j = 0; j < 4; ++j) acc2[i][j] = floatx4{0.f, 0.f, 0.f, 0.f};
    for (int s = 0; s < 8; ++s) {
        half8 bfr[4];
        #pragma unroll
        for (int nt = 0; nt < 4; ++nt)
            bfr[nt] = *(const half8*)&sm.X[nt * 16 + mr][s * 32 + hf * 8];
        #pragma unroll
        for (int mt = 0; mt < 4; ++mt) {
            half8 afr = *(const half8*)(W2T + (((wv * 4 + mt) * 8 + s) << 9) + lane * 8);
            #pragma unroll
            for (int nt = 0; nt < 4; ++nt)
                acc2[mt][nt] = MFMA16(afr, bfr[nt], acc2[mt][nt]);
        }
    }
    __syncthreads();   // X reads done before overwrite

    // ---- epilogue 2: relu(x2 + b2) -> X[r][n], packed b64 ----
    #pragma unroll
    for (int mt = 0; mt < 4; ++mt) {
        int n0 = wv * 64 + mt * 16 + hf * 4;
        float4 bb = *(const float4*)&b2[n0];
        float bv[4] = {bb.x, bb.y, bb.z, bb.w};
        #pragma unroll
        for (int nt = 0; nt < 4; ++nt) {
            int r = nt * 16 + mr;
            half4v h;
            #pragma unroll
            for (int u = 0; u < 4; ++u) {
                float v = acc2[mt][nt][u] + bv[u];
                h[u] = (_Float16)(v > 0.f ? v : 0.f);
            }
            *(half4v*)&sm.X[r][n0] = h;
        }
    }
    __syncthreads();

    // ---- layer 3: pred = x2 @ W3 + b3 (fp32), 6 broadcast copies ----
    {
        int r = t >> 2, qd = t & 3;
        float sum = 0.f;
        #pragma unroll
        for (int dd = 0; dd < 64; dd += 8) {
            half8 xv = *(const half8*)&sm.X[r][qd * 64 + dd];
            float4 w0 = *(const float4*)(W3 + qd * 64 + dd);
            float4 w1 = *(const float4*)(W3 + qd * 64 + dd + 4);
            sum += (float)xv[0] * w0.x + (float)xv[1] * w0.y
                 + (float)xv[2] * w0.z + (float)xv[3] * w0.w
                 + (float)xv[4] * w1.x + (float)xv[5] * w1.y
                 + (float)xv[6] * w1.z + (float)xv[7] * w1.w;
        }
        sum += __shfl_xor(sum, 1);
        sum += __shfl_xor(sum, 2);
        if (qd == 0) {
            int i = i0 + (r >> 3), j = j0 + (r & 7);
            if (i < 300 && j < 300) {
                float pred = sum + b3[0];
                int base = b * 90000 + i * 300 + j;
                #pragma unroll
                for (int lo = 0; lo < 6; ++lo) out[lo * 180000 + base] = pred;
            }
        }
    }
}

// ---------------------------------------------------------------------------
extern "C" void kernel_launch(void* const* d_in, const int* in_sizes, int n_in,
                              void* d_out, int out_size, void* d_ws, size_t ws_size,
                              hipStream_t stream) {
    (void)in_sizes; (void)n_in; (void)out_size; (void)ws_size;
    const float* hs   = (const float*)d_in[0];
    const float* Wq   = (const float*)d_in[1];
    const float* bq   = (const float*)d_in[2];
    const float* Wk   = (const float*)d_in[3];
    const float* bk   = (const float*)d_in[4];
    const float* Wsub = (const float*)d_in[5];
    const float* bsub = (const float*)d_in[6];
    const float* Wobj = (const float*)d_in[7];
    const float* bobj = (const float*)d_in[8];
    const float* Wg   = (const float*)d_in[9];
    const float* bg   = (const float*)d_in[10];
    const float* W1   = (const float*)d_in[11];
    const float* b1   = (const float*)d_in[12];
    const float* W2   = (const float*)d_in[13];
    const float* b2   = (const float*)d_in[14];
    const float* W3   = (const float*)d_in[15];
    const float* b3   = (const float*)d_in[16];

    char* ws = (char*)d_ws;
    float* g_ws   = (float*)ws;                  // 8,400 f
    _Float16* WT  = (_Float16*)(ws + 33600);     // 17*65536 h  (2.23 MB)
    _Float16* PQt = WT + 17 * 65536;             // 2*38*256*56 = 1,089,536 h
    _Float16* PKt = PQt + 1089536;               // 1,089,536 h
    // total ws use: ~6.7 MB

    k_wprep<<<544, 256, 0, stream>>>(Wq, Wk, Wsub, Wobj, W1, W2, WT);
    k_projpq<<<280, 256, 0, stream>>>(hs, WT, bq, bk, bsub, bobj, Wg,
                                      PQt, PKt, g_ws);
    k_fused<<<2888, 256, 0, stream>>>(PQt, PKt, g_ws, b1, WT + 16 * 65536,
                                      b2, W3, b3, bg, (float*)d_out);
}

// Round 7
// 147.779 us; speedup vs baseline: 8.6182x; 1.1389x over previous
//
#include <hip/hip_runtime.h>

// ---------------------------------------------------------------------------
// CustomDeformableDetrMLPPredictionHead — MI355X (gfx950), round 6.
// Same as round 5 except k_fused: layer-3 is fused into layer-2's register
// epilogue (shuffle-reduce over hf + tiny red[] in the dead gate array),
// deleting the second X LDS round-trip (16 b64 writes + 8 b128 reads and
// 2 barriers per lane).  Gates use __expf.  Pass-0 one-hot A-frags built
// with 2 selects instead of 8.
// ---------------------------------------------------------------------------

typedef _Float16 half8 __attribute__((ext_vector_type(8)));
typedef _Float16 half4v __attribute__((ext_vector_type(4)));
typedef float floatx4 __attribute__((ext_vector_type(4)));

#define MFMA16(a, b, c) __builtin_amdgcn_mfma_f32_16x16x32_f16((a), (b), (c), 0, 0, 0)

// ---------------- k_wprep: 17 mats -> MFMA f16 tiles (verified) ------------
__global__ __launch_bounds__(256) void k_wprep(
    const float* __restrict__ Wq, const float* __restrict__ Wk,
    const float* __restrict__ Wsub, const float* __restrict__ Wobj,
    const float* __restrict__ W1, const float* __restrict__ W2,
    _Float16* __restrict__ WT)
{
    int eid = blockIdx.x * 256 + threadIdx.x;     // 0..139263
    int mat = eid >> 13;                          // 0..16
    int rem = eid & 8191;
    int tileid = rem >> 6;
    int lane = rem & 63;
    const float* src;
    if      (mat < 6)  src = Wq + mat * 65536;
    else if (mat < 12) src = Wk + (mat - 6) * 65536;
    else if (mat == 12) src = Wsub;
    else if (mat == 13) src = Wobj;
    else if (mat == 14) src = W1;            // W1a: rows 0..255
    else if (mat == 15) src = W1 + 65536;    // W1b: rows 256..511
    else               src = W2;
    int nb = tileid >> 3, kb = tileid & 7;
    int n = nb * 16 + (lane & 15);
    int k = kb * 32 + (lane >> 4) * 8;
    half8 h;
    #pragma unroll
    for (int j = 0; j < 8; ++j) h[j] = (_Float16)src[(k + j) * 256 + n];
    *(half8*)(WT + mat * 65536 + tileid * 512 + lane * 8) = h;
}

// ---------------- k_projpq (verbatim round 5, verified) --------------------
__global__ __launch_bounds__(256) void k_projpq(
    const float* __restrict__ hs, const _Float16* __restrict__ WT,
    const float* __restrict__ bq, const float* __restrict__ bk,
    const float* __restrict__ bsub, const float* __restrict__ bobj,
    const float* __restrict__ Wg,
    _Float16* __restrict__ PQt, _Float16* __restrict__ PKt,
    float* __restrict__ g_ws)
{
    __shared__ __align__(16) _Float16 Ah[32][264];   // hs f16; reused as Pst
    __shared__ __align__(16) _Float16 X[32][264];    // Q f16

    int bid = blockIdx.x;
    int s = bid / 10, rt = bid - s * 10;
    int m0 = rt * 32;
    int qk = s & 1, rr = s >> 1;
    int l = rr % 7, b = rr / 7;
    int hs_l = (l < 6) ? l : 5;
    const float* src = hs + (hs_l * 2 + b) * 76800;
    int projmat = (l < 6) ? (qk * 6 + l) : (12 + qk);
    const _Float16* WprojT = WT + projmat * 65536;
    const _Float16* W1hT   = WT + (14 + qk) * 65536;
    const float* bias = (l < 6) ? ((qk ? bk : bq) + l * 256) : (qk ? bobj : bsub);
    _Float16* dstP = qk ? PKt : PQt;
    const float* wvec = Wg + qk * 256;
    float* gdst = g_ws + qk * 4200 + (l * 2 + b) * 300;

    int t = threadIdx.x, lane = t & 63, wv = t >> 6;
    int mr = lane & 15, hf = lane >> 4;

    // ---- stage hs rows -> Ah (f16).  8 threads/row, 32 cols each ----
    {
        int row = t >> 3, qt = t & 7;
        int m = m0 + row; if (m > 299) m = 299;
        const float* p = src + m * 256 + qt * 32;
        #pragma unroll
        for (int i = 0; i < 8; ++i) {
            float4 v = *(const float4*)(p + 4 * i);
            half4v h;
            h[0] = (_Float16)v.x; h[1] = (_Float16)v.y;
            h[2] = (_Float16)v.z; h[3] = (_Float16)v.w;
            *(half4v*)&Ah[row][qt * 32 + 4 * i] = h;
        }
    }
    __syncthreads();

    // ---- GEMM1 (flipped): Q^T = Wproj^T @ hs^T ----
    floatx4 acc[4][2];
    #pragma unroll
    for (int i = 0; i < 4; ++i)
        #pragma unroll
        for (int j = 0; j < 2; ++j) acc[i][j] = floatx4{0.f, 0.f, 0.f, 0.f};
    for (int ks = 0; ks < 8; ++ks) {
        half8 bfr[2];
        #pragma unroll
        for (int nt = 0; nt < 2; ++nt)
            bfr[nt] = *(const half8*)&Ah[nt * 16 + mr][ks * 32 + hf * 8];
        #pragma unroll
        for (int mt = 0; mt < 4; ++mt) {
            half8 afr = *(const half8*)(WprojT + (((wv * 4 + mt) * 8 + ks) << 9) + lane * 8);
            #pragma unroll
            for (int nt = 0; nt < 2; ++nt)
                acc[mt][nt] = MFMA16(afr, bfr[nt], acc[mt][nt]);
        }
    }

    // ---- epilogue 1: Q + bias -> X[row][qcol], packed b64 ----
    #pragma unroll
    for (int mt = 0; mt < 4; ++mt) {
        int n0 = wv * 64 + mt * 16 + hf * 4;
        float4 bb = *(const float4*)&bias[n0];
        float bv[4] = {bb.x, bb.y, bb.z, bb.w};
        #pragma unroll
        for (int nt = 0; nt < 2; ++nt) {
            int r = nt * 16 + mr;
            half4v h;
            #pragma unroll
            for (int u = 0; u < 4; ++u) h[u] = (_Float16)(acc[mt][nt][u] + bv[u]);
            *(half4v*)&X[r][n0] = h;
        }
    }
    __syncthreads();

    // ---- gq/gk: row dots with wvec -> g_ws ----
    {
        int row = t >> 3, qt = t & 7;
        float sum = 0.f;
        #pragma unroll
        for (int i = 0; i < 32; i += 8) {
            half8 xv = *(const half8*)&X[row][qt * 32 + i];
            const float* wp = wvec + qt * 32 + i;
            float4 w0 = *(const float4*)wp;
            float4 w1 = *(const float4*)(wp + 4);
            sum += (float)xv[0] * w0.x + (float)xv[1] * w0.y
                 + (float)xv[2] * w0.z + (float)xv[3] * w0.w
                 + (float)xv[4] * w1.x + (float)xv[5] * w1.y
                 + (float)xv[6] * w1.z + (float)xv[7] * w1.w;
        }
        sum += __shfl_xor(sum, 1);
        sum += __shfl_xor(sum, 2);
        sum += __shfl_xor(sum, 4);
        int m = m0 + row;
        if (qt == 0 && m < 300) gdst[m] = sum;
    }

    // ---- GEMM2 (flipped): P^T = W1h^T @ Q^T ----
    floatx4 acc2[4][2];
    #pragma unroll
    for (int i = 0; i < 4; ++i)
        #pragma unroll
        for (int j = 0; j < 2; ++j) acc2[i][j] = floatx4{0.f, 0.f, 0.f, 0.f};
    for (int ks = 0; ks < 8; ++ks) {
        half8 bfr[2];
        #pragma unroll
        for (int nt = 0; nt < 2; ++nt)
            bfr[nt] = *(const half8*)&X[nt * 16 + mr][ks * 32 + hf * 8];
        #pragma unroll
        for (int mt = 0; mt < 4; ++mt) {
            half8 afr = *(const half8*)(W1hT + (((wv * 4 + mt) * 8 + ks) << 9) + lane * 8);
            #pragma unroll
            for (int nt = 0; nt < 2; ++nt)
                acc2[mt][nt] = MFMA16(afr, bfr[nt], acc2[mt][nt]);
        }
    }

    // ---- epilogue 2: P -> Pst (reuse Ah), packed b64 ----
    #pragma unroll
    for (int mt = 0; mt < 4; ++mt) {
        int n0 = wv * 64 + mt * 16 + hf * 4;
        #pragma unroll
        for (int nt = 0; nt < 2; ++nt) {
            int r = nt * 16 + mr;
            half4v h;
            #pragma unroll
            for (int u = 0; u < 4; ++u) h[u] = (_Float16)acc2[mt][nt][u];
            *(half4v*)&Ah[r][n0] = h;
        }
    }
    __syncthreads();

    // ---- coalesced store: dst[((b*38+it)*256+n)*56 + l*8 + io], 16B ----
    for (int z = 0; z < 4; ++z) {
        int task = z * 256 + t;            // 0..1023
        int it4 = task >> 8, n = task & 255;
        int it = rt * 4 + it4;
        if (it < 38) {
            half8 h;
            #pragma unroll
            for (int io = 0; io < 8; ++io) h[io] = Ah[it4 * 8 + io][n];
            *(half8*)(dstP + ((size_t)(b * 38 + it) * 256 + n) * 56 + l * 8) = h;
        }
    }
}

// ---------------- k_fused -------------------------------------------------
// grid 2*38*38 = 2888, block 256 (4 waves; waves split 256 out-cols).
// LDS: union{Pt 36.9KB, X 33.8KB} + gate 1.8KB = 38.7KB -> 4 blocks/CU.
__global__ __launch_bounds__(256, 4) void k_fused(
    const _Float16* __restrict__ PQt, const _Float16* __restrict__ PKt,
    const float* __restrict__ g_ws, const float* __restrict__ b1,
    const _Float16* __restrict__ W2T, const float* __restrict__ b2,
    const float* __restrict__ W3, const float* __restrict__ b3,
    const float* __restrict__ bg, float* __restrict__ out)
{
    union SM {
        _Float16 Pt[256][72];   // [n][k], k = l*8+io (0..55); 56..63 zero pad
        _Float16 X[64][264];    // [r][col]
    };
    __shared__ __align__(16) SM sm;
    __shared__ float gate[7][64];   // gates; reused as red[4][64] after x1

    int t = threadIdx.x, lane = t & 63, wv = t >> 6;
    int mr = lane & 15, hf = lane >> 4;
    int bid = blockIdx.x;
    int b = bid / 1444, rem = bid - b * 1444;
    int it = rem / 38, jt = rem - it * 38;
    int i0 = it * 8, j0 = jt * 8;

    // ---- gates: gate[l][r], r = (i_off<<3)|j_off (verified) ----
    float bg0 = bg[0];
    for (int task = t; task < 448; task += 256) {
        int l = task >> 6, row = task & 63;
        int i = i0 + (row >> 3); if (i > 299) i = 299;
        int j = j0 + (row & 7);  if (j > 299) j = 299;
        float z = g_ws[l * 600 + b * 300 + i] + g_ws[4200 + l * 600 + b * 300 + j] + bg0;
        gate[l][row] = 1.0f / (1.0f + __expf(-z));
    }

    // ---- x1-build (flipped): x1^T = [PQ;PK]^T @ G^T, two 64-K passes ----
    floatx4 acc1[4][4];
    #pragma unroll
    for (int i = 0; i < 4; ++i)
        #pragma unroll
        for (int j = 0; j < 4; ++j) acc1[i][j] = floatx4{0.f, 0.f, 0.f, 0.f};

    #pragma unroll
    for (int pass = 0; pass < 2; ++pass) {
        const _Float16* src = pass ? PKt : PQt;
        int tb = pass ? jt : it;
        const _Float16* gp = src + ((size_t)(b * 38 + tb) * 256 + t) * 56;
        __syncthreads();   // prev-pass Pt reads done / gates visible (pass 0)
        #pragma unroll
        for (int l = 0; l < 7; ++l)
            *(half8*)&sm.Pt[t][l * 8] = *(const half8*)(gp + l * 8);
        *(half8*)&sm.Pt[t][56] = half8{};   // zero pad
        __syncthreads();   // staging visible

        #pragma unroll
        for (int ktl = 0; ktl < 2; ++ktl) {
            int l = ktl * 4 + hf;            // source layer for this k-octet
            half8 bfr[4];
            #pragma unroll
            for (int nt = 0; nt < 4; ++nt) {
                int r = nt * 16 + mr;
                float g = (l < 7) ? gate[l][r] : 0.f;
                _Float16 gh = (_Float16)g;
                const _Float16 hz = (_Float16)0.f;
                half8 f = {};
                if (pass == 0) {             // jstar = nt*2 + (mr>>3)
                    f[nt * 2]     = (mr < 8)  ? gh : hz;
                    f[nt * 2 + 1] = (mr >= 8) ? gh : hz;
                } else {                     // jstar = mr & 7
                    #pragma unroll
                    for (int j = 0; j < 8; ++j)
                        f[j] = (j == (mr & 7)) ? gh : hz;
                }
                bfr[nt] = f;
            }
            #pragma unroll
            for (int mt = 0; mt < 4; ++mt) {
                half8 afr = *(const half8*)&sm.Pt[wv * 64 + mt * 16 + mr][ktl * 32 + hf * 8];
                #pragma unroll
                for (int nt = 0; nt < 4; ++nt)
                    acc1[mt][nt] = MFMA16(afr, bfr[nt], acc1[mt][nt]);
            }
        }
    }
    __syncthreads();   // all Pt reads + gate reads done; X may overwrite union

    // ---- epilogue 1: relu(x1 + b1) -> X[r][n], packed b64 ----
    #pragma unroll
    for (int mt = 0; mt < 4; ++mt) {
        int n0 = wv * 64 + mt * 16 + hf * 4;
        float4 bb = *(const float4*)&b1[n0];
        float bv[4] = {bb.x, bb.y, bb.z, bb.w};
        #pragma unroll
        for (int nt = 0; nt < 4; ++nt) {
            int r = nt * 16 + mr;
            half4v h;
            #pragma unroll
            for (int u = 0; u < 4; ++u) {
                float v = acc1[mt][nt][u] + bv[u];
                h[u] = (_Float16)(v > 0.f ? v : 0.f);
            }
            *(half4v*)&sm.X[r][n0] = h;
        }
    }
    __syncthreads();

    // ---- layer 2 (flipped): x2^T = W2^T @ x1^T ----
    floatx4 acc2[4][4];
    #pragma unroll
    for (int i = 0; i < 4; ++i)
        #pragma unroll
        for (int j = 0; j < 4; ++j) acc2[i][j] = floatx4{0.f, 0.f, 0.f, 0.f};
    for (int s = 0; s < 8; ++s) {
        half8 bfr[4];
        #pragma unroll
        for (int nt = 0; nt < 4; ++nt)
            bfr[nt] = *(const half8*)&sm.X[nt * 16 + mr][s * 32 + hf * 8];
        #pragma unroll
        for (int mt = 0; mt < 4; ++mt) {
            half8 afr = *(const half8*)(W2T + (((wv * 4 + mt) * 8 + s) << 9) + lane * 8);
            #pragma unroll
            for (int nt = 0; nt < 4; ++nt)
                acc2[mt][nt] = MFMA16(afr, bfr[nt], acc2[mt][nt]);
        }
    }

    // ---- fused epilogue 2 + layer 3: p[row] = relu(x2+b2) . W3 ----
    // lane holds cols n0(mt)..+3, rows nt*16+mr.  Reduce over hf (cols of
    // this wave) via shuffles, stash per-wave partials in red (= gate mem).
    {
        float* red = &gate[0][0];            // 256 floats; gates are dead
        float p[4] = {0.f, 0.f, 0.f, 0.f};
        #pragma unroll
        for (int mt = 0; mt < 4; ++mt) {
            int n0 = wv * 64 + mt * 16 + hf * 4;
            float4 bb = *(const float4*)&b2[n0];
            float4 w3 = *(const float4*)&W3[n0];
            float bv[4] = {bb.x, bb.y, bb.z, bb.w};
            float wv3[4] = {w3.x, w3.y, w3.z, w3.w};
            #pragma unroll
            for (int nt = 0; nt < 4; ++nt)
                #pragma unroll
                for (int u = 0; u < 4; ++u) {
                    float v = acc2[mt][nt][u] + bv[u];
                    v = v > 0.f ? v : 0.f;
                    p[nt] += v * wv3[u];
                }
        }
        #pragma unroll
        for (int nt = 0; nt < 4; ++nt) {
            p[nt] += __shfl_xor(p[nt], 16);
            p[nt] += __shfl_xor(p[nt], 32);
        }
        if (hf == 0) {
            #pragma unroll
            for (int nt = 0; nt < 4; ++nt)
                red[wv * 64 + nt * 16 + mr] = p[nt];
        }
        __syncthreads();
        if (t < 64) {
            float pred = red[t] + red[64 + t] + red[128 + t] + red[192 + t] + b3[0];
            int i = i0 + (t >> 3), j = j0 + (t & 7);
            if (i < 300 && j < 300) {
                int base = b * 90000 + i * 300 + j;
                #pragma unroll
                for (int lo = 0; lo < 6; ++lo) out[lo * 180000 + base] = pred;
            }
        }
    }
}

// ---------------------------------------------------------------------------
extern "C" void kernel_launch(void* const* d_in, const int* in_sizes, int n_in,
                              void* d_out, int out_size, void* d_ws, size_t ws_size,
                              hipStream_t stream) {
    (void)in_sizes; (void)n_in; (void)out_size; (void)ws_size;
    const float* hs   = (const float*)d_in[0];
    const float* Wq   = (const float*)d_in[1];
    const float* bq   = (const float*)d_in[2];
    const float* Wk   = (const float*)d_in[3];
    const float* bk   = (const float*)d_in[4];
    const float* Wsub = (const float*)d_in[5];
    const float* bsub = (const float*)d_in[6];
    const float* Wobj = (const float*)d_in[7];
    const float* bobj = (const float*)d_in[8];
    const float* Wg   = (const float*)d_in[9];
    const float* bg   = (const float*)d_in[10];
    const float* W1   = (const float*)d_in[11];
    const float* b1   = (const float*)d_in[12];
    const float* W2   = (const float*)d_in[13];
    const float* b2   = (const float*)d_in[14];
    const float* W3   = (const float*)d_in[15];
    const float* b3   = (const float*)d_in[16];

    char* ws = (char*)d_ws;
    float* g_ws   = (float*)ws;                  // 8,400 f
    _Float16* WT  = (_Float16*)(ws + 33600);     // 17*65536 h  (2.23 MB)
    _Float16* PQt = WT + 17 * 65536;             // 2*38*256*56 = 1,089,536 h
    _Float16* PKt = PQt + 1089536;               // 1,089,536 h
    // total ws use: ~6.7 MB

    k_wprep<<<544, 256, 0, stream>>>(Wq, Wk, Wsub, Wobj, W1, W2, WT);
    k_projpq<<<280, 256, 0, stream>>>(hs, WT, bq, bk, bsub, bobj, Wg,
                                      PQt, PKt, g_ws);
    k_fused<<<2888, 256, 0, stream>>>(PQt, PKt, g_ws, b1, WT + 16 * 65536,
                                      b2, W3, b3, bg, (float*)d_out);
}